// Round 8
// baseline (408.852 us; speedup 1.0000x reference)
//
#include <hip/hip_runtime.h>
#include <hip/hip_bf16.h>

// local_NCC_3d v6b (v6 with ext_vector types for nontemporal builtins).
// k_pack2: P2[g][h][w][d] = (im[d], im[min(d+1,127)]) float2 — halves gather
//          requests in K1 (16 b64 vs 32 b32), exact fp32.
// K1: warp + 14 stat channels + 9-tap D box-sum + fused grad-L2; chunked XCD
//     swizzle; nontemporal S stores (keep L2 for the gather working set).
// K2: W box-sum in-place, running-sum taps, nontemporal streams.
// K3: H box-sum + cc, full-row staging, running-sum.
// K4: finalize.
// ws: S[14*NVOX] f32 | P2[4*NVOX] float2 | pg2[8192] f64 | pcc[1024] f64.

#define NVOX (128*128*128)   // 2^21
#define NGRP 4
#define NCH 14

typedef float f32x4 __attribute__((ext_vector_type(4)));
typedef float f32x2 __attribute__((ext_vector_type(2)));

// ------------------------------------------------ pack: img -> P2
__global__ __launch_bounds__(256) void k_pack2(const float* __restrict__ img,
                                               f32x2* __restrict__ P2)
{
    int idx = blockIdx.x * 256 + threadIdx.x;       // over 4*NVOX
    int v = idx & (NVOX - 1);
    int g = idx >> 21;
    int d = v & 127;
    const float* im = img + (size_t)g * NVOX;
    float a = im[v];
    float b = (d < 127) ? im[v + 1] : a;
    f32x2 pv; pv.x = a; pv.y = b;
    __builtin_nontemporal_store(pv, &P2[idx]);
}

// ------------------------------------------------ K1: warp + stats + D-sum + g2
__global__ __launch_bounds__(256) void k_warp_stats_d(
    const f32x2* __restrict__ P2, const float* __restrict__ flo,
    float* __restrict__ S, double* __restrict__ pg2)
{
    __shared__ float jt[NGRP][256];
    int t = threadIdx.x;
    // chunked XCD swizzle: XCD x gets 1024 consecutive blocks (16 h-rows);
    // concurrent gather window ~2.6MB/XCD <= 4MB L2.
    int b = ((blockIdx.x & 7) << 10) | (blockIdx.x >> 3);
    int v = b * 256 + t;
    int d = v & 127;
    int w = (v >> 7) & 127;
    int h = v >> 14;
    float g2s = 0.f;

#pragma unroll
    for (int g = 0; g < NGRP; ++g) {
        const float* f = flo + (size_t)g * 3 * NVOX;
        float fx = f[v], fy = f[NVOX + v], fz = f[2 * NVOX + v];
        if (h < 127) {
            float a = f[v + 16384] - fx;
            float bb = f[NVOX + v + 16384] - fy;
            float c = f[2 * NVOX + v + 16384] - fz;
            g2s += a * a + bb * bb + c * c;
        }
        if (w < 127) {
            float a = f[v + 128] - fx;
            float bb = f[NVOX + v + 128] - fy;
            float c = f[2 * NVOX + v + 128] - fz;
            g2s += a * a + bb * bb + c * c;
        }
        if (d < 127) {
            float a = f[v + 1] - fx;
            float bb = f[NVOX + v + 1] - fy;
            float c = f[2 * NVOX + v + 1] - fz;
            g2s += a * a + bb * bb + c * c;
        }
        float ch = fminf(fmaxf(fx + (float)h, 0.f), 127.f);
        float cw = fminf(fmaxf(fy + (float)w, 0.f), 127.f);
        float cd = fminf(fmaxf(fz + (float)d, 0.f), 127.f);
        float h0f = floorf(ch), w0f = floorf(cw), d0f = floorf(cd);
        int h0 = (int)h0f, w0 = (int)w0f, d0 = (int)d0f;
        float fh = ch - h0f, fw = cw - w0f, fd = cd - d0f;
        int h1 = min(h0 + 1, 127), w1 = min(w0 + 1, 127);
        const f32x2* P = P2 + (size_t)g * NVOX;
        f32x2 q00 = P[h0 * 16384 + w0 * 128 + d0];
        f32x2 q01 = P[h0 * 16384 + w1 * 128 + d0];
        f32x2 q10 = P[h1 * 16384 + w0 * 128 + d0];
        f32x2 q11 = P[h1 * 16384 + w1 * 128 + d0];
        float c00 = q00.x + fd * (q00.y - q00.x);
        float c01 = q01.x + fd * (q01.y - q01.x);
        float c10 = q10.x + fd * (q10.y - q10.x);
        float c11 = q11.x + fd * (q11.y - q11.x);
        float c0 = c00 + fw * (c01 - c00);
        float c1 = c10 + fw * (c11 - c10);
        jt[g][t] = c0 + fh * (c1 - c0);
    }
    __syncthreads();

    float s[NCH];
#pragma unroll
    for (int c = 0; c < NCH; ++c) s[c] = 0.f;
    int lbase = t & 128;
#pragma unroll
    for (int k = -4; k <= 4; ++k) {
        int q = d + k;
        if ((unsigned)q < 128u) {
            int tq = lbase + q;
            float j0 = jt[0][tq], j1 = jt[1][tq], j2 = jt[2][tq], j3 = jt[3][tq];
            float tm = 0.25f * (j0 + j1 + j2 + j3);
            s[0] += tm;       s[1] += tm * tm;
            s[2] += j0;  s[3] += j0 * j0;  s[4]  += tm * j0;
            s[5] += j1;  s[6] += j1 * j1;  s[7]  += tm * j1;
            s[8] += j2;  s[9] += j2 * j2;  s[10] += tm * j2;
            s[11] += j3; s[12] += j3 * j3; s[13] += tm * j3;
        }
    }
#pragma unroll
    for (int c = 0; c < NCH; ++c)
        __builtin_nontemporal_store(s[c], &S[(size_t)c * NVOX + v]);

    double val = (double)g2s;
    for (int off = 32; off; off >>= 1) val += __shfl_down(val, off, 64);
    __shared__ double wsum[4];
    int lane = t & 63, wid = t >> 6;
    if (lane == 0) wsum[wid] = val;
    __syncthreads();
    if (t == 0) pg2[b] = wsum[0] + wsum[1] + wsum[2] + wsum[3];
}

// ------------------------------------------------ K2: W box-sum, running-sum taps
__global__ __launch_bounds__(256) void k_sum_w(float* __restrict__ S)
{
    __shared__ float tile[128 * 68];                // [w][dd], stride 68
    int t = threadIdx.x;
    int bid = blockIdx.x;
    int half = bid & 1;
    int chh = bid >> 1;                             // c*128 + h
    size_t base = (size_t)chh * 16384 + half * 64;
#pragma unroll
    for (int it = 0; it < 8; ++it) {
        int idx4 = it * 256 + t;
        int w = idx4 >> 4, dq = idx4 & 15;
        f32x4 vv = __builtin_nontemporal_load(
            (const f32x4*)(S + base + (size_t)w * 128 + dq * 4));
        *(f32x4*)(tile + w * 68 + dq * 4) = vv;
    }
    __syncthreads();
    int dq = t & 15;
    int wq = t >> 4;                                // 0..15, 8 w each
    int w0 = wq * 8;
    f32x4 s = {0.f, 0.f, 0.f, 0.f};
#pragma unroll
    for (int k = -4; k <= 4; ++k) {
        int q = w0 + k;
        if ((unsigned)q < 128u)
            s += *(const f32x4*)(tile + q * 68 + dq * 4);
    }
    __builtin_nontemporal_store(s, (f32x4*)(S + base + (size_t)w0 * 128 + dq * 4));
#pragma unroll
    for (int wi = 1; wi < 8; ++wi) {
        int w = w0 + wi;
        int qa = w + 4;
        if (qa < 128)
            s += *(const f32x4*)(tile + qa * 68 + dq * 4);
        int qr = w - 5;
        if (qr >= 0)
            s -= *(const f32x4*)(tile + qr * 68 + dq * 4);
        __builtin_nontemporal_store(s, (f32x4*)(S + base + (size_t)w * 128 + dq * 4));
    }
}

// ------------------------------------------------ K3: H box-sum + cc (full rows)
__device__ __forceinline__ float cc4(f32x4 I, f32x4 I2, f32x4 J, f32x4 J2, f32x4 IJ)
{
    const float inv = 1.0f / 729.0f;
    f32x4 cr = IJ - J * I * inv;
    f32x4 iv = I2 - I * I * inv;
    f32x4 jv = J2 - J * J * inv;
    f32x4 cc = cr * cr / (iv * jv + 1e-5f);
    return cc.x + cc.y + cc.z + cc.w;
}

#define LOADH(c, a0, a1)                                                       \
    do {                                                                       \
        const float* cp = S + (size_t)(c) * NVOX + cbase;                      \
        _Pragma("unroll")                                                      \
        for (int it = 0; it < 3; ++it) {                                       \
            int idx = it * 256 + t;                                            \
            if (idx < 640) {                    /* 40 rows x 16 quads */       \
                int row = idx >> 4, dqu = idx & 15;                            \
                int rr = r0 + row;                                             \
                f32x4 vv = {0.f, 0.f, 0.f, 0.f};                               \
                if ((unsigned)rr < 128u)                                       \
                    vv = __builtin_nontemporal_load(                           \
                        (const f32x4*)(cp + (size_t)rr * 16384 + dqu * 4));    \
                int la = row * 65 + dqu * 4;                                   \
                tile[la] = vv.x; tile[la + 1] = vv.y;                          \
                tile[la + 2] = vv.z; tile[la + 3] = vv.w;                      \
            }                                                                  \
        }                                                                      \
        __syncthreads();                                                       \
        {                                                                      \
            int hl = hg * 2;                                                   \
            f32x4 sum = {0.f, 0.f, 0.f, 0.f};                                  \
            _Pragma("unroll")                                                  \
            for (int k = 0; k < 9; ++k) {                                      \
                const float* tp = tile + (hl + k) * 65 + dq * 4;               \
                sum.x += tp[0]; sum.y += tp[1]; sum.z += tp[2]; sum.w += tp[3];\
            }                                                                  \
            a0 = sum;                                                          \
            const float* ta = tile + (hl + 9) * 65 + dq * 4;                   \
            const float* tr = tile + hl * 65 + dq * 4;                         \
            sum.x += ta[0] - tr[0]; sum.y += ta[1] - tr[1];                    \
            sum.z += ta[2] - tr[2]; sum.w += ta[3] - tr[3];                    \
            a1 = sum;                                                          \
        }                                                                      \
        __syncthreads();                                                       \
    } while (0)

__global__ __launch_bounds__(256) void k_sum_h_cc(const float* __restrict__ S,
                                                  double* __restrict__ pcc)
{
    __shared__ float tile[40 * 65];                 // 10.4 KB
    int t = threadIdx.x;
    int bid = blockIdx.x;                           // 128w * 4hq * 2dh
    int dh = bid & 1;
    int hq = (bid >> 1) & 3;
    int w = bid >> 3;
    int r0 = hq * 32 - 4;                           // first staged global row
    size_t cbase = (size_t)w * 128 + dh * 64;
    int dq = t & 15;                                // d-quad within 64
    int hg = t >> 4;                                // 0..15, 2 h-outputs each

    f32x4 Ia0, Ia1, I2a0, I2a1, Ja0, Ja1, J2a0, J2a1, IJa0, IJa1;
    float lsum = 0.f;

    LOADH(0, Ia0, Ia1);
    LOADH(1, I2a0, I2a1);
    for (int g = 0; g < NGRP; ++g) {
        LOADH(2 + 3 * g, Ja0, Ja1);
        LOADH(3 + 3 * g, J2a0, J2a1);
        LOADH(4 + 3 * g, IJa0, IJa1);
        lsum += cc4(Ia0, I2a0, Ja0, J2a0, IJa0);
        lsum += cc4(Ia1, I2a1, Ja1, J2a1, IJa1);
    }

    double val = (double)lsum;
    for (int off = 32; off; off >>= 1) val += __shfl_down(val, off, 64);
    __shared__ double wsum[4];
    int lane = t & 63, wid = t >> 6;
    if (lane == 0) wsum[wid] = val;
    __syncthreads();
    if (t == 0) pcc[bid] = wsum[0] + wsum[1] + wsum[2] + wsum[3];
}

// ------------------------------------------------ K4: finalize
__global__ __launch_bounds__(256) void k_finalize(const double* __restrict__ pg2,
                                                  const double* __restrict__ pcc,
                                                  float* __restrict__ out)
{
    double s_cc = 0.0, s_g2 = 0.0;
    for (int i = threadIdx.x; i < 1024; i += 256) s_cc += pcc[i];
    for (int i = threadIdx.x; i < 8192; i += 256) s_g2 += pg2[i];
    for (int off = 32; off; off >>= 1) {
        s_cc += __shfl_down(s_cc, off, 64);
        s_g2 += __shfl_down(s_g2, off, 64);
    }
    __shared__ double a[4], b[4];
    int lane = threadIdx.x & 63, wid = threadIdx.x >> 6;
    if (lane == 0) { a[wid] = s_cc; b[wid] = s_g2; }
    __syncthreads();
    if (threadIdx.x == 0) {
        double cc_sum = a[0] + a[1] + a[2] + a[3];
        double g2_sum = b[0] + b[1] + b[2] + b[3];
        double lncc = -cc_sum / (4.0 * (double)NVOX);
        double g2 = g2_sum / (3.0 * 12.0 * 127.0 * 128.0 * 128.0);
        out[0] = (float)(lncc + g2);
    }
}

extern "C" void kernel_launch(void* const* d_in, const int* in_sizes, int n_in,
                              void* d_out, int out_size, void* d_ws, size_t ws_size,
                              hipStream_t stream)
{
    const float* img = (const float*)d_in[0];   // [4][1][128^3]
    const float* flo = (const float*)d_in[1];   // [4][3][128^3]
    float* out = (float*)d_out;

    const size_t S_BYTES  = (size_t)NCH * NVOX * 4;        // 117,440,512
    const size_t P2_BYTES = (size_t)NGRP * NVOX * 8;       // 67,108,864
    float* S = (float*)d_ws;
    f32x2* P2 = (f32x2*)((char*)d_ws + S_BYTES);
    double* pg2 = (double*)((char*)d_ws + S_BYTES + P2_BYTES);  // 8192 f64
    double* pcc = pg2 + 8192;                                   // 1024 f64

    k_pack2<<<(NGRP * NVOX) / 256, 256, 0, stream>>>(img, P2);  // 32768 blocks
    k_warp_stats_d<<<NVOX / 256, 256, 0, stream>>>(P2, flo, S, pg2); // 8192
    k_sum_w<<<NCH * 128 * 2, 256, 0, stream>>>(S);              // 3584 blocks
    k_sum_h_cc<<<1024, 256, 0, stream>>>(S, pcc);               // 128w*4hq*2dh
    k_finalize<<<1, 256, 0, stream>>>(pg2, pcc, out);
}

// Round 9
// 353.234 us; speedup vs baseline: 1.1575x; 1.1575x over previous
//
#include <hip/hip_runtime.h>
#include <hip/hip_bf16.h>

// local_NCC_3d v7.
// K1: direct-gather warp (forced-MLP: all 32 gather issues pinned before any
//     consumption via sched_barrier), 14 stat channels, 9-tap D box-sum,
//     fused grad-L2; chunked XCD swizzle; nontemporal S stores.
// K2: W box-sum in-place, running-sum taps, nontemporal streams.
// K3: H box-sum + cc, full-row staging, running-sum.
// K4: finalize.
// ws: S[14*NVOX] f32 | pg2[8192] f64 | pcc[1024] f64.

#define NVOX (128*128*128)   // 2^21
#define NGRP 4
#define NCH 14

typedef float f32x4 __attribute__((ext_vector_type(4)));

// ------------------------------------------------ K1: warp + stats + D-sum + g2
__global__ __launch_bounds__(256, 2) void k_warp_stats_d(
    const float* __restrict__ img, const float* __restrict__ flo,
    float* __restrict__ S, double* __restrict__ pg2)
{
    __shared__ float jt[NGRP][256];
    int t = threadIdx.x;
    // chunked XCD swizzle: XCD x gets 1024 consecutive blocks (16 h-rows);
    // concurrent gather window ~2.6MB/XCD <= 4MB L2.
    int b = ((blockIdx.x & 7) << 10) | (blockIdx.x >> 3);
    int v = b * 256 + t;
    int d = v & 127;
    int w = (v >> 7) & 127;
    int h = v >> 14;

    // ---- phase 1: coalesced flow loads, all groups
    float fx[NGRP], fy[NGRP], fz[NGRP];
#pragma unroll
    for (int g = 0; g < NGRP; ++g) {
        const float* f = flo + (size_t)g * 3 * NVOX;
        fx[g] = f[v];
        fy[g] = f[NVOX + v];
        fz[g] = f[2 * NVOX + v];
    }

    // ---- phase 2: all 32 gather offsets
    float fh[NGRP], fw[NGRP], fd[NGRP];
    int o[NGRP][4];                      // row-pair bases: b00,b01,b10,b11 (+d0)
    int d1o[NGRP];                       // d1 - d0 (0 or 1)
#pragma unroll
    for (int g = 0; g < NGRP; ++g) {
        float ch = fminf(fmaxf(fx[g] + (float)h, 0.f), 127.f);
        float cw = fminf(fmaxf(fy[g] + (float)w, 0.f), 127.f);
        float cd = fminf(fmaxf(fz[g] + (float)d, 0.f), 127.f);
        float h0f = floorf(ch), w0f = floorf(cw), d0f = floorf(cd);
        int h0 = (int)h0f, w0 = (int)w0f, d0 = (int)d0f;
        fh[g] = ch - h0f; fw[g] = cw - w0f; fd[g] = cd - d0f;
        int h1 = min(h0 + 1, 127), w1 = min(w0 + 1, 127);
        d1o[g] = (d0 < 127) ? 1 : 0;
        o[g][0] = (h0 * 128 + w0) * 128 + d0;
        o[g][1] = (h0 * 128 + w1) * 128 + d0;
        o[g][2] = (h1 * 128 + w0) * 128 + d0;
        o[g][3] = (h1 * 128 + w1) * 128 + d0;
    }

    // ---- phase 3: issue all 32 gathers (static indexing; pinned early)
    float gv[NGRP][8];
#pragma unroll
    for (int g = 0; g < NGRP; ++g) {
        const float* im = img + (size_t)g * NVOX;
        gv[g][0] = im[o[g][0]]; gv[g][1] = im[o[g][0] + d1o[g]];
        gv[g][2] = im[o[g][1]]; gv[g][3] = im[o[g][1] + d1o[g]];
        gv[g][4] = im[o[g][2]]; gv[g][5] = im[o[g][2] + d1o[g]];
        gv[g][6] = im[o[g][3]]; gv[g][7] = im[o[g][3] + d1o[g]];
    }
    __builtin_amdgcn_sched_barrier(0);   // keep gather issues above consumers

    // ---- phase 4: g2 regularizer (independent; fills gather latency)
    float g2s = 0.f;
#pragma unroll
    for (int g = 0; g < NGRP; ++g) {
        const float* f = flo + (size_t)g * 3 * NVOX;
        if (h < 127) {
            float a = f[v + 16384] - fx[g];
            float bb = f[NVOX + v + 16384] - fy[g];
            float c = f[2 * NVOX + v + 16384] - fz[g];
            g2s += a * a + bb * bb + c * c;
        }
        if (w < 127) {
            float a = f[v + 128] - fx[g];
            float bb = f[NVOX + v + 128] - fy[g];
            float c = f[2 * NVOX + v + 128] - fz[g];
            g2s += a * a + bb * bb + c * c;
        }
        if (d < 127) {
            float a = f[v + 1] - fx[g];
            float bb = f[NVOX + v + 1] - fy[g];
            float c = f[2 * NVOX + v + 1] - fz[g];
            g2s += a * a + bb * bb + c * c;
        }
    }

    // ---- phase 5: trilinear lerps
#pragma unroll
    for (int g = 0; g < NGRP; ++g) {
        float c00 = gv[g][0] + fd[g] * (gv[g][1] - gv[g][0]);
        float c01 = gv[g][2] + fd[g] * (gv[g][3] - gv[g][2]);
        float c10 = gv[g][4] + fd[g] * (gv[g][5] - gv[g][4]);
        float c11 = gv[g][6] + fd[g] * (gv[g][7] - gv[g][6]);
        float c0 = c00 + fw[g] * (c01 - c00);
        float c1 = c10 + fw[g] * (c11 - c10);
        jt[g][t] = c0 + fh[g] * (c1 - c0);
    }
    __syncthreads();

    // ---- phase 6: 9-tap D box-sum of 14 product channels
    float s[NCH];
#pragma unroll
    for (int c = 0; c < NCH; ++c) s[c] = 0.f;
    int lbase = t & 128;
#pragma unroll
    for (int k = -4; k <= 4; ++k) {
        int q = d + k;
        if ((unsigned)q < 128u) {
            int tq = lbase + q;
            float j0 = jt[0][tq], j1 = jt[1][tq], j2 = jt[2][tq], j3 = jt[3][tq];
            float tm = 0.25f * (j0 + j1 + j2 + j3);
            s[0] += tm;       s[1] += tm * tm;
            s[2] += j0;  s[3] += j0 * j0;  s[4]  += tm * j0;
            s[5] += j1;  s[6] += j1 * j1;  s[7]  += tm * j1;
            s[8] += j2;  s[9] += j2 * j2;  s[10] += tm * j2;
            s[11] += j3; s[12] += j3 * j3; s[13] += tm * j3;
        }
    }
#pragma unroll
    for (int c = 0; c < NCH; ++c)
        __builtin_nontemporal_store(s[c], &S[(size_t)c * NVOX + v]);

    // ---- g2 reduction
    double val = (double)g2s;
    for (int off = 32; off; off >>= 1) val += __shfl_down(val, off, 64);
    __shared__ double wsum[4];
    int lane = t & 63, wid = t >> 6;
    if (lane == 0) wsum[wid] = val;
    __syncthreads();
    if (t == 0) pg2[b] = wsum[0] + wsum[1] + wsum[2] + wsum[3];
}

// ------------------------------------------------ K2: W box-sum, running-sum taps
__global__ __launch_bounds__(256) void k_sum_w(float* __restrict__ S)
{
    __shared__ float tile[128 * 68];                // [w][dd], stride 68
    int t = threadIdx.x;
    int bid = blockIdx.x;
    int half = bid & 1;
    int chh = bid >> 1;                             // c*128 + h
    size_t base = (size_t)chh * 16384 + half * 64;
#pragma unroll
    for (int it = 0; it < 8; ++it) {
        int idx4 = it * 256 + t;
        int w = idx4 >> 4, dq = idx4 & 15;
        f32x4 vv = __builtin_nontemporal_load(
            (const f32x4*)(S + base + (size_t)w * 128 + dq * 4));
        *(f32x4*)(tile + w * 68 + dq * 4) = vv;
    }
    __syncthreads();
    int dq = t & 15;
    int wq = t >> 4;                                // 0..15, 8 w each
    int w0 = wq * 8;
    f32x4 s = {0.f, 0.f, 0.f, 0.f};
#pragma unroll
    for (int k = -4; k <= 4; ++k) {
        int q = w0 + k;
        if ((unsigned)q < 128u)
            s += *(const f32x4*)(tile + q * 68 + dq * 4);
    }
    __builtin_nontemporal_store(s, (f32x4*)(S + base + (size_t)w0 * 128 + dq * 4));
#pragma unroll
    for (int wi = 1; wi < 8; ++wi) {
        int w = w0 + wi;
        int qa = w + 4;
        if (qa < 128)
            s += *(const f32x4*)(tile + qa * 68 + dq * 4);
        int qr = w - 5;
        if (qr >= 0)
            s -= *(const f32x4*)(tile + qr * 68 + dq * 4);
        __builtin_nontemporal_store(s, (f32x4*)(S + base + (size_t)w * 128 + dq * 4));
    }
}

// ------------------------------------------------ K3: H box-sum + cc (full rows)
__device__ __forceinline__ float cc4(f32x4 I, f32x4 I2, f32x4 J, f32x4 J2, f32x4 IJ)
{
    const float inv = 1.0f / 729.0f;
    f32x4 cr = IJ - J * I * inv;
    f32x4 iv = I2 - I * I * inv;
    f32x4 jv = J2 - J * J * inv;
    f32x4 cc = cr * cr / (iv * jv + 1e-5f);
    return cc.x + cc.y + cc.z + cc.w;
}

#define LOADH(c, a0, a1)                                                       \
    do {                                                                       \
        const float* cp = S + (size_t)(c) * NVOX + cbase;                      \
        _Pragma("unroll")                                                      \
        for (int it = 0; it < 3; ++it) {                                       \
            int idx = it * 256 + t;                                            \
            if (idx < 640) {                    /* 40 rows x 16 quads */       \
                int row = idx >> 4, dqu = idx & 15;                            \
                int rr = r0 + row;                                             \
                f32x4 vv = {0.f, 0.f, 0.f, 0.f};                               \
                if ((unsigned)rr < 128u)                                       \
                    vv = __builtin_nontemporal_load(                           \
                        (const f32x4*)(cp + (size_t)rr * 16384 + dqu * 4));    \
                int la = row * 65 + dqu * 4;                                   \
                tile[la] = vv.x; tile[la + 1] = vv.y;                          \
                tile[la + 2] = vv.z; tile[la + 3] = vv.w;                      \
            }                                                                  \
        }                                                                      \
        __syncthreads();                                                       \
        {                                                                      \
            int hl = hg * 2;                                                   \
            f32x4 sum = {0.f, 0.f, 0.f, 0.f};                                  \
            _Pragma("unroll")                                                  \
            for (int k = 0; k < 9; ++k) {                                      \
                const float* tp = tile + (hl + k) * 65 + dq * 4;               \
                sum.x += tp[0]; sum.y += tp[1]; sum.z += tp[2]; sum.w += tp[3];\
            }                                                                  \
            a0 = sum;                                                          \
            const float* ta = tile + (hl + 9) * 65 + dq * 4;                   \
            const float* tr = tile + hl * 65 + dq * 4;                         \
            sum.x += ta[0] - tr[0]; sum.y += ta[1] - tr[1];                    \
            sum.z += ta[2] - tr[2]; sum.w += ta[3] - tr[3];                    \
            a1 = sum;                                                          \
        }                                                                      \
        __syncthreads();                                                       \
    } while (0)

__global__ __launch_bounds__(256) void k_sum_h_cc(const float* __restrict__ S,
                                                  double* __restrict__ pcc)
{
    __shared__ float tile[40 * 65];                 // 10.4 KB
    int t = threadIdx.x;
    int bid = blockIdx.x;                           // 128w * 4hq * 2dh
    int dh = bid & 1;
    int hq = (bid >> 1) & 3;
    int w = bid >> 3;
    int r0 = hq * 32 - 4;                           // first staged global row
    size_t cbase = (size_t)w * 128 + dh * 64;
    int dq = t & 15;                                // d-quad within 64
    int hg = t >> 4;                                // 0..15, 2 h-outputs each

    f32x4 Ia0, Ia1, I2a0, I2a1, Ja0, Ja1, J2a0, J2a1, IJa0, IJa1;
    float lsum = 0.f;

    LOADH(0, Ia0, Ia1);
    LOADH(1, I2a0, I2a1);
    for (int g = 0; g < NGRP; ++g) {
        LOADH(2 + 3 * g, Ja0, Ja1);
        LOADH(3 + 3 * g, J2a0, J2a1);
        LOADH(4 + 3 * g, IJa0, IJa1);
        lsum += cc4(Ia0, I2a0, Ja0, J2a0, IJa0);
        lsum += cc4(Ia1, I2a1, Ja1, J2a1, IJa1);
    }

    double val = (double)lsum;
    for (int off = 32; off; off >>= 1) val += __shfl_down(val, off, 64);
    __shared__ double wsum[4];
    int lane = t & 63, wid = t >> 6;
    if (lane == 0) wsum[wid] = val;
    __syncthreads();
    if (t == 0) pcc[bid] = wsum[0] + wsum[1] + wsum[2] + wsum[3];
}

// ------------------------------------------------ K4: finalize
__global__ __launch_bounds__(256) void k_finalize(const double* __restrict__ pg2,
                                                  const double* __restrict__ pcc,
                                                  float* __restrict__ out)
{
    double s_cc = 0.0, s_g2 = 0.0;
    for (int i = threadIdx.x; i < 1024; i += 256) s_cc += pcc[i];
    for (int i = threadIdx.x; i < 8192; i += 256) s_g2 += pg2[i];
    for (int off = 32; off; off >>= 1) {
        s_cc += __shfl_down(s_cc, off, 64);
        s_g2 += __shfl_down(s_g2, off, 64);
    }
    __shared__ double a[4], b[4];
    int lane = threadIdx.x & 63, wid = threadIdx.x >> 6;
    if (lane == 0) { a[wid] = s_cc; b[wid] = s_g2; }
    __syncthreads();
    if (threadIdx.x == 0) {
        double cc_sum = a[0] + a[1] + a[2] + a[3];
        double g2_sum = b[0] + b[1] + b[2] + b[3];
        double lncc = -cc_sum / (4.0 * (double)NVOX);
        double g2 = g2_sum / (3.0 * 12.0 * 127.0 * 128.0 * 128.0);
        out[0] = (float)(lncc + g2);
    }
}

extern "C" void kernel_launch(void* const* d_in, const int* in_sizes, int n_in,
                              void* d_out, int out_size, void* d_ws, size_t ws_size,
                              hipStream_t stream)
{
    const float* img = (const float*)d_in[0];   // [4][1][128^3]
    const float* flo = (const float*)d_in[1];   // [4][3][128^3]
    float* out = (float*)d_out;

    const size_t S_BYTES = (size_t)NCH * NVOX * 4;          // 117,440,512
    float* S = (float*)d_ws;
    double* pg2 = (double*)((char*)d_ws + S_BYTES);         // 8192 f64
    double* pcc = pg2 + 8192;                               // 1024 f64

    k_warp_stats_d<<<NVOX / 256, 256, 0, stream>>>(img, flo, S, pg2); // 8192
    k_sum_w<<<NCH * 128 * 2, 256, 0, stream>>>(S);          // 3584 blocks
    k_sum_h_cc<<<1024, 256, 0, stream>>>(S, pcc);           // 128w*4hq*2dh
    k_finalize<<<1, 256, 0, stream>>>(pg2, pcc, out);
}